// Round 1
// baseline (2189.778 us; speedup 1.0000x reference)
//
#include <hip/hip_runtime.h>

#define N_NODES 50000
#define N_EDGES 400000
#define EMB 32
#define NREL 8
#define NLAYER 5

// ---------------- setup kernels ----------------

__global__ __launch_bounds__(256) void zero_kernel(int* __restrict__ p, int n) {
    int i = blockIdx.x * 256 + threadIdx.x;
    if (i < n) p[i] = 0;
}

__global__ __launch_bounds__(256) void hist_kernel(const int* __restrict__ ei,
                                                   const int* __restrict__ et,
                                                   int* __restrict__ deg,
                                                   int* __restrict__ relcnt) {
    int e = blockIdx.x * 256 + threadIdx.x;
    if (e < N_EDGES) {
        int d = ei[N_EDGES + e];           // dst = edge_index[1]
        atomicAdd(&deg[d], 1);
        atomicAdd(&relcnt[d * NREL + et[e]], 1);
    }
}

// single-block scan: exclusive prefix over deg -> row_ptr[0..N], row_ptr[N]=E
__global__ __launch_bounds__(1024) void scan_kernel(const int* __restrict__ deg,
                                                    int* __restrict__ row_ptr) {
    __shared__ int wtot[16];
    __shared__ int pwt[16];
    __shared__ int carry_s;
    int tid = threadIdx.x;
    int lane = tid & 63;
    int w = tid >> 6;
    if (tid == 0) carry_s = 0;
    __syncthreads();
    for (int base = 0; base < N_NODES; base += 1024) {
        int i = base + tid;
        int v = (i < N_NODES) ? deg[i] : 0;
        int incl = v;
        #pragma unroll
        for (int off = 1; off < 64; off <<= 1) {
            int t = __shfl_up(incl, off, 64);
            if (lane >= off) incl += t;
        }
        if (lane == 63) wtot[w] = incl;
        __syncthreads();
        if (tid == 0) {
            int c = carry_s, run = 0;
            #pragma unroll
            for (int j = 0; j < 16; j++) { pwt[j] = c + run; run += wtot[j]; }
            carry_s = c + run;
        }
        __syncthreads();
        if (i < N_NODES) row_ptr[i] = pwt[w] + incl - v;
        __syncthreads();
    }
    if (tid == 0) row_ptr[N_NODES] = carry_s;
}

__global__ __launch_bounds__(256) void inv_kernel(const int* __restrict__ deg,
                                                  const int* __restrict__ relcnt,
                                                  float* __restrict__ invdeg,
                                                  float* __restrict__ invcnt) {
    int n = blockIdx.x * 256 + threadIdx.x;
    if (n < N_NODES) {
        int d = deg[n];
        invdeg[n] = 1.0f / (float)(d > 0 ? d : 1);
        #pragma unroll
        for (int r = 0; r < NREL; r++) {
            int c = relcnt[n * NREL + r];
            invcnt[n * NREL + r] = 1.0f / (float)(c > 0 ? c : 1);
        }
    }
}

__global__ __launch_bounds__(256) void scatter_kernel(const int* __restrict__ ei,
                                                      const int* __restrict__ et,
                                                      const float* __restrict__ ed,
                                                      const int* __restrict__ row_ptr,
                                                      int* __restrict__ cursor,
                                                      int* __restrict__ packed,
                                                      float* __restrict__ dist_s) {
    int e = blockIdx.x * 256 + threadIdx.x;
    if (e < N_EDGES) {
        int d = ei[N_EDGES + e];
        int pos = row_ptr[d] + atomicAdd(&cursor[d], 1);
        packed[pos] = ei[e] | (et[e] << 16);   // src < 65536, type < 8
        dist_s[pos] = ed[e];
    }
}

// ---------------- fc: h0 = relu(x @ fc_W + fc_b) ----------------

__global__ __launch_bounds__(256) void fc_kernel(const float* __restrict__ x,
                                                 const float* __restrict__ W,
                                                 const float* __restrict__ b,
                                                 float* __restrict__ h) {
    __shared__ __align__(16) float xt[8][EMB];
    int tid = threadIdx.x;
    int nl = tid >> 5, lane = tid & 31;
    int n0 = blockIdx.x * 8;
    xt[tid >> 5][tid & 31] = x[n0 * EMB + tid];
    __syncthreads();
    float acc = b[lane];
    #pragma unroll
    for (int i = 0; i < EMB; i++) acc += xt[nl][i] * W[i * EMB + lane];
    h[(n0 + nl) * EMB + lane] = fmaxf(acc, 0.0f);
}

// ---------------- per-layer node transforms ----------------
// Hr[n,r,:] = h[n] @ rgcn_W[l,r];  rootr = h @ rgcn_root + rgcn_bias;
// rootn = h @ nn_root + nn_bias
__global__ __launch_bounds__(256) void transform_kernel(const float* __restrict__ h,
                                                        const float* __restrict__ Wr,
                                                        const float* __restrict__ rootW_r,
                                                        const float* __restrict__ bias_r,
                                                        const float* __restrict__ rootW_n,
                                                        const float* __restrict__ bias_n,
                                                        float* __restrict__ Hr,
                                                        float* __restrict__ rootr,
                                                        float* __restrict__ rootn) {
    __shared__ __align__(16) float ht[8][EMB];
    int tid = threadIdx.x;
    int nl = tid >> 5, lane = tid & 31;
    int n0 = blockIdx.x * 8;
    ht[tid >> 5][tid & 31] = h[n0 * EMB + tid];
    __syncthreads();
    int n = n0 + nl;
    #pragma unroll
    for (int r = 0; r < NREL; r++) {
        float acc = 0.0f;
        #pragma unroll
        for (int i = 0; i < EMB; i++) acc += ht[nl][i] * Wr[(r * EMB + i) * EMB + lane];
        Hr[(n * NREL + r) * EMB + lane] = acc;
    }
    float accR = bias_r[lane];
    float accN = bias_n[lane];
    #pragma unroll
    for (int i = 0; i < EMB; i++) {
        float hv = ht[nl][i];
        accR += hv * rootW_r[i * EMB + lane];
        accN += hv * rootW_n[i * EMB + lane];
    }
    rootr[n * EMB + lane] = accR;
    rootn[n * EMB + lane] = accN;
}

// ---------------- fused aggregation (one half-wave per dst node) ----------------
__global__ __launch_bounds__(256) void agg_kernel(const float* __restrict__ h,
                                                  const float* __restrict__ Hr,
                                                  const float* __restrict__ rootr,
                                                  const float* __restrict__ rootn,
                                                  const int* __restrict__ packed,
                                                  const float* __restrict__ dist_s,
                                                  const int* __restrict__ row_ptr,
                                                  const float* __restrict__ invdeg,
                                                  const float* __restrict__ invcnt,
                                                  const float* __restrict__ W1,
                                                  const float* __restrict__ b1,
                                                  const float* __restrict__ W2,
                                                  const float* __restrict__ b2,
                                                  float* __restrict__ hout) {
    __shared__ __align__(16) float P_lds[8][33][EMB];   // 33 KB
    __shared__ __align__(16) float hid_stage[8][EMB];   // 1 KB
    __shared__ __align__(16) float Wbuf[4][EMB][EMB];   // 16 KB (4 k-rows of W2)
    int tid = threadIdx.x;
    int dl = tid >> 5, lane = tid & 31;
    int d = blockIdx.x * 8 + dl;                        // N divisible by 8: no guard

    float P[33];
    #pragma unroll
    for (int k = 0; k < 33; k++) P[k] = 0.0f;
    float acc_r = 0.0f;

    int pb = row_ptr[d], pe = row_ptr[d + 1];
    float w10 = W1[lane];
    float b1v = b1[lane];
    for (int p = pb; p < pe; p++) {
        int pk = packed[p];
        int s = pk & 0xFFFF;
        int r = pk >> 16;
        float dist = dist_s[p];
        float hv = h[s * EMB + lane];
        acc_r += Hr[(s * NREL + r) * EMB + lane] * invcnt[d * NREL + r];
        // hidden[e][lane] = relu(dist*W1[0,lane] + W1[1+r,lane] + b1[lane])
        float hid = fmaxf(dist * w10 + W1[(1 + r) * EMB + lane] + b1v, 0.0f);
        hid_stage[dl][lane] = hid;      // broadcast within half-wave via LDS
        #pragma unroll
        for (int j = 0; j < 8; j++) {
            float4 h4 = ((const float4*)&hid_stage[dl][0])[j];
            P[4 * j + 0] += h4.x * hv;
            P[4 * j + 1] += h4.y * hv;
            P[4 * j + 2] += h4.z * hv;
            P[4 * j + 3] += h4.w * hv;
        }
        P[32] += hv;                    // ones row (for b2 contribution)
    }

    #pragma unroll
    for (int k = 0; k < 33; k++) P_lds[dl][k][lane] = P[k];
    __syncthreads();

    // contraction: acc_n[o] = sum_{k,i} P[k][i] * W2[k, i*32+o]  (+ b2 row)
    float acc_n = 0.0f;
    for (int kc = 0; kc < 8; kc++) {
        {   // stage 4 rows of W2 (4*1024 floats) coalesced
            const float4* srcp = (const float4*)(W2 + kc * 4 * 1024);
            float4* dstp = (float4*)&Wbuf[0][0][0];
            dstp[tid] = srcp[tid];
            dstp[tid + 256] = srcp[tid + 256];
            dstp[tid + 512] = srcp[tid + 512];
            dstp[tid + 768] = srcp[tid + 768];
        }
        __syncthreads();
        #pragma unroll
        for (int kk = 0; kk < 4; kk++) {
            int k = kc * 4 + kk;
            const float4* Pr = (const float4*)&P_lds[dl][k][0];
            const float* Wp = &Wbuf[kk][0][lane];
            #pragma unroll
            for (int j = 0; j < 8; j++) {
                float4 p4 = Pr[j];
                acc_n += p4.x * Wp[(4 * j + 0) * EMB];
                acc_n += p4.y * Wp[(4 * j + 1) * EMB];
                acc_n += p4.z * Wp[(4 * j + 2) * EMB];
                acc_n += p4.w * Wp[(4 * j + 3) * EMB];
            }
        }
        __syncthreads();
    }
    {   // b2 (ones) row
        const float4* Pr = (const float4*)&P_lds[dl][32][0];
        #pragma unroll
        for (int j = 0; j < 8; j++) {
            float4 p4 = Pr[j];
            acc_n += p4.x * b2[(4 * j + 0) * EMB + lane];
            acc_n += p4.y * b2[(4 * j + 1) * EMB + lane];
            acc_n += p4.z * b2[(4 * j + 2) * EMB + lane];
            acc_n += p4.w * b2[(4 * j + 3) * EMB + lane];
        }
    }

    float hd = h[d * EMB + lane];
    float o_r = fmaxf(rootr[d * EMB + lane] + acc_r, 0.0f);
    float o_n = fmaxf(rootn[d * EMB + lane] + acc_n * invdeg[d], 0.0f);
    hout[d * EMB + lane] = hd + o_r + o_n;
}

// ---------------- launch ----------------

extern "C" void kernel_launch(void* const* d_in, const int* in_sizes, int n_in,
                              void* d_out, int out_size, void* d_ws, size_t ws_size,
                              hipStream_t stream) {
    const float* x        = (const float*)d_in[0];
    const int*   ei       = (const int*)d_in[1];
    const int*   et       = (const int*)d_in[2];
    const float* ed       = (const float*)d_in[3];
    const float* fcW      = (const float*)d_in[4];
    const float* fcb      = (const float*)d_in[5];
    const float* rgcnW    = (const float*)d_in[6];
    const float* rgcnRoot = (const float*)d_in[7];
    const float* rgcnBias = (const float*)d_in[8];
    const float* W1       = (const float*)d_in[9];
    const float* b1       = (const float*)d_in[10];
    const float* W2       = (const float*)d_in[11];
    const float* b2       = (const float*)d_in[12];
    const float* nnRoot   = (const float*)d_in[13];
    const float* nnBias   = (const float*)d_in[14];

    float* ws = (float*)d_ws;
    float* h_a    = ws;  ws += (size_t)N_NODES * EMB;
    float* h_b    = ws;  ws += (size_t)N_NODES * EMB;
    float* Hr     = ws;  ws += (size_t)N_NODES * NREL * EMB;
    float* rootr  = ws;  ws += (size_t)N_NODES * EMB;
    float* rootn  = ws;  ws += (size_t)N_NODES * EMB;
    float* dist_s = ws;  ws += (size_t)N_EDGES;
    float* invdeg = ws;  ws += (size_t)N_NODES;
    float* invcnt = ws;  ws += (size_t)N_NODES * NREL;
    int* packed   = (int*)ws;      ws += (size_t)N_EDGES;
    int* row_ptr  = (int*)ws;      ws += (size_t)(N_NODES + 1);
    int* deg      = (int*)ws;      ws += (size_t)N_NODES;      // deg..cursor contiguous (10N ints)
    int* relcnt   = (int*)ws;      ws += (size_t)N_NODES * NREL;
    int* cursor   = (int*)ws;      ws += (size_t)N_NODES;
    (void)in_sizes; (void)n_in; (void)out_size; (void)ws_size;

    zero_kernel<<<(10 * N_NODES + 255) / 256, 256, 0, stream>>>(deg, 10 * N_NODES);
    hist_kernel<<<(N_EDGES + 255) / 256, 256, 0, stream>>>(ei, et, deg, relcnt);
    scan_kernel<<<1, 1024, 0, stream>>>(deg, row_ptr);
    inv_kernel<<<(N_NODES + 255) / 256, 256, 0, stream>>>(deg, relcnt, invdeg, invcnt);
    scatter_kernel<<<(N_EDGES + 255) / 256, 256, 0, stream>>>(ei, et, ed, row_ptr,
                                                              cursor, packed, dist_s);
    fc_kernel<<<N_NODES / 8, 256, 0, stream>>>(x, fcW, fcb, h_a);

    const float* hin = h_a;
    float* houtb = h_b;
    for (int l = 0; l < NLAYER; l++) {
        transform_kernel<<<N_NODES / 8, 256, 0, stream>>>(
            hin, rgcnW + (size_t)l * NREL * EMB * EMB,
            rgcnRoot + (size_t)l * EMB * EMB, rgcnBias + (size_t)l * EMB,
            nnRoot + (size_t)l * EMB * EMB, nnBias + (size_t)l * EMB,
            Hr, rootr, rootn);
        float* dst = (l == NLAYER - 1) ? (float*)d_out : houtb;
        agg_kernel<<<N_NODES / 8, 256, 0, stream>>>(
            hin, Hr, rootr, rootn, packed, dist_s, row_ptr, invdeg, invcnt,
            W1, b1, W2, b2, dst);
        float* old_in = (float*)hin;
        hin = dst;
        houtb = old_in;
    }
}